// Round 9
// baseline (245.604 us; speedup 1.0000x reference)
//
#include <hip/hip_runtime.h>
#include <hip/hip_bf16.h>

typedef unsigned short ushort_t;
typedef __attribute__((ext_vector_type(4))) short bf16x4_t;   // 4 x bf16 (2 VGPRs)
typedef __attribute__((ext_vector_type(8))) short short8;     // 8 x bf16
typedef __attribute__((ext_vector_type(4))) unsigned short ushort4_t;
typedef __attribute__((ext_vector_type(4))) float f32x4;
typedef __attribute__((ext_vector_type(2))) unsigned int uint2_t;
typedef __attribute__((ext_vector_type(4))) unsigned int uint4_t;

#define LOG2E 1.44269504088896340736f

__device__ __forceinline__ unsigned short f2bf(float f) {
    unsigned int u = __float_as_uint(f);
    u += 0x7fffu + ((u >> 16) & 1u);          // round-to-nearest-even
    return (unsigned short)(u >> 16);
}

__device__ __forceinline__ unsigned int pk2bf(float a, float b) {
    union { __hip_bfloat162 h2; unsigned int u; } cvt;
    cvt.h2 = __float22bfloat162_rn(make_float2(a, b));   // v_cvt_pk_bf16_f32
    return cvt.u;
}

__device__ __forceinline__ void gl_lds16(const ushort_t* g, ushort_t* l) {
    __builtin_amdgcn_global_load_lds(
        (const __attribute__((address_space(1))) unsigned int*)g,
        (__attribute__((address_space(3))) unsigned int*)l, 16, 0, 0);
}

// K=16 bf16 MFMA: A/B = 4 bf16 (2 VGPRs). S^T C-frag == PV A-frag for this shape.
__device__ __forceinline__ f32x4 mfma16(uint2_t a, uint2_t b, f32x4 c) {
    union { uint2_t u; bf16x4_t s; } ua, ub;
    ua.u = a; ub.u = b;
    return __builtin_amdgcn_mfma_f32_16x16x16bf16_1k(ua.s, ub.s, c, 0, 0, 0);
}

// LPT dispatch table for the split attention grid (24 items x 64 bh).
// iters: split item = qt+1, unsplit item = 2qt+2; sorted descending.
// gr: 0 = key-half [0,(qt+1)*64), 1 = diagonal half, 2 = unsplit.
__device__ const signed char QT_TAB[24] =
    {15,15,7,14,14,13,13,6,12,12,11,11,5,10,10,9,9,4,8,8,3,2,1,0};
__device__ const signed char GR_TAB[24] =
    { 0, 1,2, 0, 1, 0, 1,2, 0, 1, 0, 1,2, 0, 1,0,1,2,0,1,2,2,2,2};

// ---------------------------------------------------------------------------
// Merged conversion kernel (one launch instead of two):
//  blocks [0, 4096):    x (fp32 [8192][1024]) -> xb (bf16, same layout)
//  blocks [4096, 5632): w (fp32 [1024][3072]) -> wt (bf16 [3072][1024]) transp
// ---------------------------------------------------------------------------
__global__ __launch_bounds__(256) void cvt_xw(
    const float* __restrict__ x, ushort_t* __restrict__ xb,
    const float* __restrict__ w, ushort_t* __restrict__ wt)
{
    __shared__ ushort_t Ts[64][40];           // [n][k] (w path only)
    const int bid = blockIdx.x;
    const int tid = threadIdx.x;
    if (bid < 4096) {
        const size_t i = ((size_t)bid * 256 + tid) * 8;
        const float4 a = *(const float4*)(x + i);
        const float4 b = *(const float4*)(x + i + 4);
        uint4_t o;
        o[0] = pk2bf(a.x, a.y); o[1] = pk2bf(a.z, a.w);
        o[2] = pk2bf(b.x, b.y); o[3] = pk2bf(b.z, b.w);
        *(uint4_t*)(xb + i) = o;
    } else {
        const int wb = bid - 4096;
        const int k0 = (wb & 31) * 32, n0 = (wb >> 5) * 64;
        const int kr = tid >> 3, nc = (tid & 7) * 8;
        const float* g = w + (size_t)(k0 + kr) * 3072 + n0 + nc;
        const float4 a = *(const float4*)g;
        const float4 b = *(const float4*)(g + 4);
        const float vals[8] = {a.x, a.y, a.z, a.w, b.x, b.y, b.z, b.w};
#pragma unroll
        for (int j = 0; j < 8; ++j) Ts[nc + j][kr] = f2bf(vals[j]);
        __syncthreads();
        const int nr = tid >> 2, kc = (tid & 3) * 8;
        const short8 v = *(const short8*)&Ts[nr][kc];
        *(short8*)(wt + (size_t)(n0 + nr) * 1024 + k0 + kc) = v;
    }
}

// ---------------------------------------------------------------------------
// qkv = xb @ wt^T + b.  BM=128, BN=128, BK=32.
// T3+T4 pipeline: 3 LDS buffers, prefetch distance 2, raw s_barrier with
// counted `s_waitcnt vmcnt(4)` (never 0 in main loop).  (unchanged, round 3)
// ---------------------------------------------------------------------------
__global__ __launch_bounds__(256) void qkv_gemm(
    const ushort_t* __restrict__ xb, const ushort_t* __restrict__ wt,
    const float* __restrict__ bq,
    ushort_t* __restrict__ kws, ushort_t* __restrict__ qws,
    ushort_t* __restrict__ vws)
{
    __shared__ ushort_t As[3][128 * 32];      // [buf][row][k] (k XOR-swizzled)
    __shared__ ushort_t Bs[3][128 * 32];

    const int tid  = threadIdx.x;
    const int m0   = blockIdx.x * 128;
    const int n0   = blockIdx.y * 128;
    const int wv   = tid >> 6;
    const int lane = tid & 63;
    const int qr   = lane & 15;
    const int quad = lane >> 4;
    const int wm   = (wv >> 1) * 64;
    const int wn   = (wv & 1) * 64;

    const int lr   = lane >> 2;               // 0..15
    const int csw  = (lane & 3) ^ ((lr >> 1) & 3);
    const ushort_t* gA = xb + (size_t)(m0 + wv*32 + lr) * 1024 + csw*8;
    const ushort_t* gB = wt + (size_t)(n0 + wv*32 + lr) * 1024 + csw*8;
    const int sdst = wv * 1024;               // ushort offset within a buffer

    const int swq = quad ^ ((qr >> 1) & 3);

    f32x4 acc[4][4];
#pragma unroll
    for (int i = 0; i < 4; ++i)
#pragma unroll
        for (int j = 0; j < 4; ++j) acc[i][j] = (f32x4){0.f, 0.f, 0.f, 0.f};

    // prologue: stage tiles 0 and 1 into bufs 0 and 1 (8 loads in flight)
    gl_lds16(gA,             (ushort_t*)As + sdst);
    gl_lds16(gA + 16*1024,   (ushort_t*)As + sdst + 512);
    gl_lds16(gB,             (ushort_t*)Bs + sdst);
    gl_lds16(gB + 16*1024,   (ushort_t*)Bs + sdst + 512);
    gl_lds16(gA + 32,            (ushort_t*)As + 4096 + sdst);
    gl_lds16(gA + 32 + 16*1024,  (ushort_t*)As + 4096 + sdst + 512);
    gl_lds16(gB + 32,            (ushort_t*)Bs + 4096 + sdst);
    gl_lds16(gB + 32 + 16*1024,  (ushort_t*)Bs + 4096 + sdst + 512);

    int bufc = 0;                             // kt % 3
    for (int kt = 0; kt < 32; ++kt) {
        if (kt < 31) asm volatile("s_waitcnt vmcnt(4)" ::: "memory");
        else         asm volatile("s_waitcnt vmcnt(0)" ::: "memory");
        __builtin_amdgcn_s_barrier();         // buf[kt%3] ready for everyone
        __builtin_amdgcn_sched_barrier(0);

        const ushort_t* cA = (const ushort_t*)As + bufc * 4096;
        const ushort_t* cB = (const ushort_t*)Bs + bufc * 4096;
        short8 af[4], bfr[4];
#pragma unroll
        for (int i = 0; i < 4; ++i)
            af[i] = *(const short8*)&cA[(wm + i*16 + qr) * 32 + swq * 8];
#pragma unroll
        for (int j = 0; j < 4; ++j)
            bfr[j] = *(const short8*)&cB[(wn + j*16 + qr) * 32 + swq * 8];

        if (kt < 30) {                        // stage tile kt+2
            int b2 = bufc + 2;
            if (b2 >= 3) b2 -= 3;
            const int k2 = (kt + 2) * 32;
            ushort_t* dA = (ushort_t*)As + b2 * 4096 + sdst;
            ushort_t* dB = (ushort_t*)Bs + b2 * 4096 + sdst;
            gl_lds16(gA + k2,            dA);
            gl_lds16(gA + k2 + 16*1024,  dA + 512);
            gl_lds16(gB + k2,            dB);
            gl_lds16(gB + k2 + 16*1024,  dB + 512);
        }

#pragma unroll
        for (int i = 0; i < 4; ++i)
#pragma unroll
            for (int j = 0; j < 4; ++j)
                acc[i][j] = __builtin_amdgcn_mfma_f32_16x16x32_bf16(
                    af[i], bfr[j], acc[i][j], 0, 0, 0);

        asm volatile("s_waitcnt lgkmcnt(0)" ::: "memory");
        bufc = (bufc == 2) ? 0 : bufc + 1;
    }

    const int nbase = n0 + wn;
    const int sec   = nbase >> 10;            // 0=K, 1=Q, 2=V
    const int h     = (nbase & 1023) >> 6;

    if (sec == 2) {
#pragma unroll
        for (int j = 0; j < 4; ++j) {
            const float bias = bq[nbase + j*16 + qr];
            const int d = j*16 + qr;
#pragma unroll
            for (int i = 0; i < 4; ++i) {
                const int m  = m0 + wm + i*16 + quad*4;
                const int bb = m >> 11;
                const int tt = m & 2047;
                ushort4_t pk;
#pragma unroll
                for (int r = 0; r < 4; ++r) pk[r] = f2bf(acc[i][j][r] + bias);
                *(ushort4_t*)&vws[((size_t)(bb*16 + h)*64 + d)*2048 + tt] = pk;
            }
        }
    } else {
        ushort_t* __restrict__ dst = (sec == 0) ? kws : qws;
#pragma unroll
        for (int j = 0; j < 4; ++j) {
            const float bias = bq[nbase + j*16 + qr];
            const int d = j*16 + qr;
#pragma unroll
            for (int i = 0; i < 4; ++i) {
#pragma unroll
                for (int r = 0; r < 4; ++r) {
                    const int m  = m0 + wm + i*16 + quad*4 + r;
                    const int bb = m >> 11;
                    const int tt = m & 2047;
                    dst[(((size_t)(bb*16 + h)) * 2048 + tt) * 64 + d] =
                        f2bf(acc[i][j][r] + bias);
                }
            }
        }
    }
}

// ---------------------------------------------------------------------------
// SPLIT causal flash attention, 32-q-rows-per-wave inner (r6) on the split
// grid (r8). Work-throughput analysis (r6 vs r8): the 32-row inner is ~35%
// cheaper per P-element (K/V LDS reads + staging amortize over 2x q-rows);
// its r6 weakness was packing (1024 blocks = one fill, no refill). Here:
// 1536 short blocks (<=16 iters) at 4/CU -> 6/CU average, refill + uniform
// lengths. Block = 256 threads / 4 waves; wave owns 32 q-rows (2 q-sets).
// Group 0 (keys [0,(qt+1)*64)): writes RAW O0 into out, l0 -> pL.
// Group 1 (diagonal half): O1 -> pO1, l1 -> pL.  Unsplit (qt<8): direct.
// attn_combine: (O0+O1)/(l0+l1), exact f32. bh = bid&63 keeps per-head K/V
// on one XCD. 36 KB LDS -> 4 blocks/CU.
// ---------------------------------------------------------------------------
__global__ __launch_bounds__(256) void attn_fwd_split(
    const ushort_t* __restrict__ kws, const ushort_t* __restrict__ qws,
    const ushort_t* __restrict__ vws, float* __restrict__ out,
    float* __restrict__ pO1, float* __restrict__ pL)
{
    constexpr int LDK = 72;                   // 64 + 8 pad (rows 16B-aligned)
    __shared__ ushort_t Ks[2][64 * LDK];      // [buf][key][d]
    __shared__ ushort_t Vs[2][64 * LDK];      // [buf][d][t]

    const int tid  = threadIdx.x;
    const int wv   = tid >> 6;                // 0..3
    const int lane = tid & 63;
    const int qr   = lane & 15;
    const int quad = lane >> 4;
    const int srow = tid >> 2;                // 0..63
    const int scol = (tid & 3) * 16;          // 0,16,32,48
    constexpr float SCL = 0.125f * LOG2E;     // 1/sqrt(64), log2 domain
    constexpr float CB  = 8.0f;               // fixed max bound (log2 units)

    const int bid  = (int)blockIdx.x;
    const int item = bid >> 6;                // 0..23, LPT order
    const int bh   = bid & 63;
    const int qt   = QT_TAB[item];
    const int gr   = GR_TAB[item];            // 0/1 = key half, 2 = unsplit
    const size_t bhT = (size_t)bh * 2048;
    const ushort_t* kbase = kws + bhT * 64;
    const ushort_t* vbase = vws + (size_t)bh * 64 * 2048;
    const int b = bh >> 4, h = bh & 15;

    const int nt    = (gr == 2) ? (2*qt + 2) : (qt + 1);
    const int tile0 = (gr == 1) ? (qt + 1) : 0;
    const int q0    = qt * 128;
    const int base  = q0 + wv*32;             // this wave's 32 q-rows
    const int qv0   = base + qr;              // softmax-domain q (q = lane&15)
    const int qv1   = qv0 + 16;
    const int row_max = base + 31;

    const ushort_t* qg0 = qws + (bhT + qv0) * 64;
    const ushort_t* qg1 = qws + (bhT + qv1) * 64;
    const short8 Qb00 = *(const short8*)(qg0 + quad*8);
    const short8 Qb01 = *(const short8*)(qg0 + 32 + quad*8);
    const short8 Qb10 = *(const short8*)(qg1 + quad*8);
    const short8 Qb11 = *(const short8*)(qg1 + 32 + quad*8);

    float l_s[2] = {0.f, 0.f};
    f32x4 Oacc[2][4];
#pragma unroll
    for (int qs = 0; qs < 2; ++qs)
#pragma unroll
        for (int dt = 0; dt < 4; ++dt) Oacc[qs][dt] = (f32x4){0.f,0.f,0.f,0.f};

    // prologue: tile0 -> regs -> buf0
    short8 kv0, kv1, vv0, vv1;
    {
        const ushort_t* kg = kbase + (size_t)(tile0*64 + srow) * 64 + scol;
        const ushort_t* vg = vbase + (size_t)srow * 2048 + tile0*64 + scol;
        kv0 = *(const short8*)(kg);     kv1 = *(const short8*)(kg + 8);
        vv0 = *(const short8*)(vg);     vv1 = *(const short8*)(vg + 8);
    }
    *(short8*)&Ks[0][srow * LDK + scol]     = kv0;
    *(short8*)&Ks[0][srow * LDK + scol + 8] = kv1;
    *(short8*)&Vs[0][srow * LDK + scol]     = vv0;
    *(short8*)&Vs[0][srow * LDK + scol + 8] = vv1;
    __syncthreads();

    for (int t = 0; t < nt; ++t) {
        const int k0  = (tile0 + t) * 64;
        const int cur = t & 1;
        const bool more = (t + 1 < nt);
        if (more) {                           // issue next-tile loads (in flight)
            const ushort_t* kg = kbase + (size_t)(k0 + 64 + srow) * 64 + scol;
            const ushort_t* vg = vbase + (size_t)srow * 2048 + k0 + 64 + scol;
            kv0 = *(const short8*)(kg);   kv1 = *(const short8*)(kg + 8);
            vv0 = *(const short8*)(vg);   vv1 = *(const short8*)(vg + 8);
        }

        if (k0 <= row_max) {
            const ushort_t* Kc = Ks[cur];
            const ushort_t* Vc = Vs[cur];
            const bool diag = (k0 + 63 > base);   // wave-uniform

            // Per 16-key chunk: S^T = K Q^T, mask, exp2, pack -> pks.
            uint2_t pks[2][4];
            float ps0 = 0.f, ps1 = 0.f;
#pragma unroll
            for (int t4 = 0; t4 < 4; ++t4) {
                const short8 kf0 = *(const short8*)&Kc[(t4*16 + qr)*LDK + quad*8];
                const short8 kf1 = *(const short8*)&Kc[(t4*16 + qr)*LDK + 32 + quad*8];
                f32x4 a = (f32x4){0.f,0.f,0.f,0.f};
                f32x4 bfr = (f32x4){0.f,0.f,0.f,0.f};
                a   = __builtin_amdgcn_mfma_f32_16x16x32_bf16(kf0, Qb00, a, 0,0,0);
                a   = __builtin_amdgcn_mfma_f32_16x16x32_bf16(kf1, Qb01, a, 0,0,0);
                bfr = __builtin_amdgcn_mfma_f32_16x16x32_bf16(kf0, Qb10, bfr, 0,0,0);
                bfr = __builtin_amdgcn_mfma_f32_16x16x32_bf16(kf1, Qb11, bfr, 0,0,0);
                if (diag) {
#pragma unroll
                    for (int r = 0; r < 4; ++r) {
                        const int key = k0 + t4*16 + quad*4 + r;
                        if (key > qv0) a[r]   = -INFINITY;
                        if (key > qv1) bfr[r] = -INFINITY;
                    }
                }
                float p0[4], p1[4];
#pragma unroll
                for (int r = 0; r < 4; ++r) {
                    p0[r] = exp2f(__builtin_fmaf(a[r],   SCL, -CB));
                    p1[r] = exp2f(__builtin_fmaf(bfr[r], SCL, -CB));
                    ps0 += p0[r];
                    ps1 += p1[r];
                }
                pks[0][t4][0] = pk2bf(p0[0], p0[1]);
                pks[0][t4][1] = pk2bf(p0[2], p0[3]);
                pks[1][t4][0] = pk2bf(p1[0], p1[1]);
                pks[1][t4][1] = pk2bf(p1[2], p1[3]);
            }
            l_s[0] += ps0;
            l_s[1] += ps1;

            // O += P V : B-frag = V[key][d] from Vs[d][t], k=quad*4..+3
            __builtin_amdgcn_s_setprio(1);
#pragma unroll
            for (int dt = 0; dt < 4; ++dt) {
#pragma unroll
                for (int t4 = 0; t4 < 4; ++t4) {
                    const uint2_t vf = *(const uint2_t*)
                        &Vc[(dt*16 + qr)*LDK + t4*16 + quad*4];
                    Oacc[0][dt] = mfma16(pks[0][t4], vf, Oacc[0][dt]);
                    Oacc[1][dt] = mfma16(pks[1][t4], vf, Oacc[1][dt]);
                }
            }
            __builtin_amdgcn_s_setprio(0);
        }

        if (more) {                           // stage tile t+1 into other buf
            *(short8*)&Ks[cur ^ 1][srow * LDK + scol]     = kv0;
            *(short8*)&Ks[cur ^ 1][srow * LDK + scol + 8] = kv1;
            *(short8*)&Vs[cur ^ 1][srow * LDK + scol]     = vv0;
            *(short8*)&Vs[cur ^ 1][srow * LDK + scol + 8] = vv1;
        }
        __syncthreads();                      // buf ready / reads of cur done
    }

    // reduce l across quads: every lane ends with its qr-row's total
    float lf[2];
#pragma unroll
    for (int qs = 0; qs < 2; ++qs) {
        float v = l_s[qs];
        v += __shfl_xor(v, 16);
        v += __shfl_xor(v, 32);
        lf[qs] = v;
    }

    if (gr == 2) {                            // unsplit: normalize + store
#pragma unroll
        for (int qs = 0; qs < 2; ++qs) {
#pragma unroll
            for (int r = 0; r < 4; ++r) {
                const float lr  = __shfl(lf[qs], quad*4 + r);
                const float inv = 1.f / lr;
                const int q = q0 + wv*32 + qs*16 + quad*4 + r;
                float* o = out + ((size_t)(b*2048 + q)) * 1024 + h*64;
#pragma unroll
                for (int dt = 0; dt < 4; ++dt)
                    o[dt*16 + qr] = Oacc[qs][dt][r] * inv;
            }
        }
    } else {                                  // split: raw partials + l
        const int qtidx = qt - 8;
#pragma unroll
        for (int qs = 0; qs < 2; ++qs) {
            if (quad == 0)                    // lane qr holds row qr's sum
                pL[((size_t)(gr*64 + bh)*8 + qtidx)*128 + wv*32 + qs*16 + qr]
                    = lf[qs];
        }
        if (gr == 0) {                        // raw O0 straight into out
#pragma unroll
            for (int qs = 0; qs < 2; ++qs) {
#pragma unroll
                for (int r = 0; r < 4; ++r) {
                    const int q = q0 + wv*32 + qs*16 + quad*4 + r;
                    float* o = out + ((size_t)(b*2048 + q)) * 1024 + h*64;
#pragma unroll
                    for (int dt = 0; dt < 4; ++dt)
                        o[dt*16 + qr] = Oacc[qs][dt][r];
                }
            }
        } else {                              // O1 -> workspace
#pragma unroll
            for (int qs = 0; qs < 2; ++qs) {
#pragma unroll
                for (int r = 0; r < 4; ++r) {
                    const int ql = wv*32 + qs*16 + quad*4 + r;
                    float* p = pO1 + (((size_t)bh*8 + qtidx)*128 + ql)*64;
#pragma unroll
                    for (int dt = 0; dt < 4; ++dt)
                        p[dt*16 + qr] = Oacc[qs][dt][r];
                }
            }
        }
    }
}

// ---------------------------------------------------------------------------
// Combine the two key-halves for qt>=8: out = (O0_raw + O1)/(l0+l1).
// Grid 512 = 8 qt x 64 bh; 256 threads, 2 threads per q-row.
// ---------------------------------------------------------------------------
__global__ __launch_bounds__(256) void attn_combine(
    float* __restrict__ out, const float* __restrict__ pO1,
    const float* __restrict__ pL)
{
    const int bid   = (int)blockIdx.x;
    const int bh    = bid & 63;
    const int qtidx = bid >> 6;               // 0..7 -> qt = 8+qtidx
    const int b = bh >> 4, h = bh & 15;
    const int q0 = (8 + qtidx) * 128;

    const int tid = threadIdx.x;
    const int row = tid >> 1;                 // 0..127
    const int d0  = (tid & 1) * 32;

    const size_t li = ((size_t)bh*8 + qtidx)*128 + row;
    const float l0 = pL[li];
    const float l1 = pL[(size_t)64*8*128 + li];
    const float inv = 1.f / (l0 + l1);

    float4* ov = (float4*)(out + ((size_t)(b*2048 + q0 + row))*1024 + h*64 + d0);
    const float4* pv = (const float4*)(pO1 + (((size_t)bh*8 + qtidx)*128 + row)*64 + d0);
#pragma unroll
    for (int j = 0; j < 8; ++j) {
        const float4 a = ov[j];
        const float4 c = pv[j];
        ov[j] = make_float4((a.x + c.x)*inv, (a.y + c.y)*inv,
                            (a.z + c.z)*inv, (a.w + c.w)*inv);
    }
}

// ---------------------------------------------------------------------------
// Fallback (round-4-equivalent attn): used if workspace is too small for the
// split partials. Grid 1024 = 16 qt x 64 bh.
// ---------------------------------------------------------------------------
__global__ __launch_bounds__(512) void attn_fwd(
    const ushort_t* __restrict__ kws, const ushort_t* __restrict__ qws,
    const ushort_t* __restrict__ vws, float* __restrict__ out)
{
    constexpr int LDK = 72;
    __shared__ ushort_t Ks[2][64 * LDK];
    __shared__ ushort_t Vs[2][64 * LDK];

    const int tid  = threadIdx.x;
    const int wv   = tid >> 6;
    const int lane = tid & 63;
    const int qr   = lane & 15;
    const int quad = lane >> 4;
    const int srow = tid >> 3;
    const int scol = (tid & 7) * 8;
    constexpr float SCL = 0.125f * LOG2E;
    constexpr float CB  = 8.0f;

    const int bid = (int)blockIdx.x;
    const int qt  = 15 - (bid >> 6);
    const int bh  = bid & 63;
    const size_t bhT = (size_t)bh * 2048;
    const ushort_t* kbase = kws + bhT * 64;
    const ushort_t* vbase = vws + (size_t)bh * 64 * 2048;
    const int b = bh >> 4, h = bh & 15;

    const int q0 = qt * 128;
    const int base = q0 + wv*16;
    const int qv0 = base + qr;

    const ushort_t* qg0 = qws + (bhT + qv0) * 64;
    const short8 Qb00 = *(const short8*)(qg0 + quad*8);
    const short8 Qb01 = *(const short8*)(qg0 + 32 + quad*8);

    float l_s = 0.f;
    f32x4 Oacc[4];
#pragma unroll
    for (int dt = 0; dt < 4; ++dt) Oacc[dt] = (f32x4){0.f,0.f,0.f,0.f};

    const int nkt = 2*qt + 2;
    const int row_max = base + 15;

    short8 kv0, vv0;
    {
        const ushort_t* kg = kbase + (size_t)srow * 64 + scol;
        const ushort_t* vg = vbase + (size_t)srow * 2048 + scol;
        kv0 = *(const short8*)(kg);
        vv0 = *(const short8*)(vg);
    }
    *(short8*)&Ks[0][srow * LDK + scol] = kv0;
    *(short8*)&Vs[0][srow * LDK + scol] = vv0;
    __syncthreads();

    for (int kt = 0; kt < nkt; ++kt) {
        const int k0 = kt * 64;
        const int cur = kt & 1;
        const bool more = (kt + 1 < nkt);
        if (more) {
            const ushort_t* kg = kbase + (size_t)(k0 + 64 + srow) * 64 + scol;
            const ushort_t* vg = vbase + (size_t)srow * 2048 + k0 + 64 + scol;
            kv0 = *(const short8*)(kg);
            vv0 = *(const short8*)(vg);
        }

        if (k0 <= row_max) {
            const ushort_t* Kc = Ks[cur];
            const ushort_t* Vc = Vs[cur];
            const bool diag = (k0 + 63 > base);

            uint2_t pks[4];
            float ps0 = 0.f;
#pragma unroll
            for (int t4 = 0; t4 < 4; ++t4) {
                const short8 kf0 = *(const short8*)&Kc[(t4*16 + qr)*LDK + quad*8];
                const short8 kf1 = *(const short8*)&Kc[(t4*16 + qr)*LDK + 32 + quad*8];
                f32x4 a = (f32x4){0.f,0.f,0.f,0.f};
                a = __builtin_amdgcn_mfma_f32_16x16x32_bf16(kf0, Qb00, a, 0,0,0);
                a = __builtin_amdgcn_mfma_f32_16x16x32_bf16(kf1, Qb01, a, 0,0,0);
                if (diag) {
#pragma unroll
                    for (int r = 0; r < 4; ++r) {
                        const int key = k0 + t4*16 + quad*4 + r;
                        if (key > qv0) a[r] = -INFINITY;
                    }
                }
                float p0[4];
#pragma unroll
                for (int r = 0; r < 4; ++r) {
                    p0[r] = exp2f(__builtin_fmaf(a[r], SCL, -CB));
                    ps0 += p0[r];
                }
                pks[t4][0] = pk2bf(p0[0], p0[1]);
                pks[t4][1] = pk2bf(p0[2], p0[3]);
            }
            l_s += ps0;

            __builtin_amdgcn_s_setprio(1);
#pragma unroll
            for (int dt = 0; dt < 4; ++dt) {
#pragma unroll
                for (int t4 = 0; t4 < 4; ++t4) {
                    const uint2_t vf = *(const uint2_t*)
                        &Vc[(dt*16 + qr)*LDK + t4*16 + quad*4];
                    Oacc[dt] = mfma16(pks[t4], vf, Oacc[dt]);
                }
            }
            __builtin_amdgcn_s_setprio(0);
        }

        if (more) {
            *(short8*)&Ks[cur ^ 1][srow * LDK + scol] = kv0;
            *(short8*)&Vs[cur ^ 1][srow * LDK + scol] = vv0;
        }
        __syncthreads();
    }

    float lf = l_s;
    lf += __shfl_xor(lf, 16);
    lf += __shfl_xor(lf, 32);
#pragma unroll
    for (int r = 0; r < 4; ++r) {
        const float lr  = __shfl(lf, quad*4 + r);
        const float inv = 1.f / lr;
        const int q = q0 + wv*16 + quad*4 + r;
        float* o = out + ((size_t)(b*2048 + q)) * 1024 + h*64;
#pragma unroll
        for (int dt = 0; dt < 4; ++dt) o[dt*16 + qr] = Oacc[dt][r] * inv;
    }
}

extern "C" void kernel_launch(void* const* d_in, const int* in_sizes, int n_in,
                              void* d_out, int out_size, void* d_ws, size_t ws_size,
                              hipStream_t stream) {
    (void)in_sizes; (void)n_in; (void)out_size;
    const float* x  = (const float*)d_in[0];
    const float* w  = (const float*)d_in[1];
    const float* bq = (const float*)d_in[2];
    float* out = (float*)d_out;

    ushort_t* kws = (ushort_t*)d_ws;
    ushort_t* qws = kws + (size_t)8388608;
    ushort_t* vws = qws + (size_t)8388608;
    ushort_t* xb  = vws + (size_t)8388608;
    ushort_t* wt  = xb  + (size_t)8388608;

    // split-attention partials live past the 80 MB mark
    float* pO1 = (float*)(wt + (size_t)8388608);            // 16 MB
    float* pL  = pO1 + (size_t)64*8*128*64;                 // 0.5 MB
    const size_t ws_need = (size_t)5*16777216               // staging buffers
                         + (size_t)64*8*128*64*4            // pO1
                         + (size_t)2*64*8*128*4;            // pL

    cvt_xw<<<5632, 256, 0, stream>>>(x, xb, w, wt);
    qkv_gemm<<<dim3(64, 24), 256, 0, stream>>>(xb, wt, bq, kws, qws, vws);
    if (ws_size >= ws_need) {
        attn_fwd_split<<<1536, 256, 0, stream>>>(kws, qws, vws, out, pO1, pL);
        attn_combine<<<512, 256, 0, stream>>>(out, pO1, pL);
    } else {
        attn_fwd<<<1024, 512, 0, stream>>>(kws, qws, vws, out);
    }
}

// Round 10
// 221.202 us; speedup vs baseline: 1.1103x; 1.1103x over previous
//
#include <hip/hip_runtime.h>
#include <hip/hip_bf16.h>

typedef unsigned short ushort_t;
typedef __attribute__((ext_vector_type(4))) short bf16x4_t;   // 4 x bf16 (2 VGPRs)
typedef __attribute__((ext_vector_type(8))) short short8;     // 8 x bf16
typedef __attribute__((ext_vector_type(4))) unsigned short ushort4_t;
typedef __attribute__((ext_vector_type(4))) float f32x4;
typedef __attribute__((ext_vector_type(2))) unsigned int uint2_t;
typedef __attribute__((ext_vector_type(4))) unsigned int uint4_t;

#define LOG2E 1.44269504088896340736f

__device__ __forceinline__ unsigned short f2bf(float f) {
    unsigned int u = __float_as_uint(f);
    u += 0x7fffu + ((u >> 16) & 1u);          // round-to-nearest-even
    return (unsigned short)(u >> 16);
}

__device__ __forceinline__ unsigned int pk2bf(float a, float b) {
    union { __hip_bfloat162 h2; unsigned int u; } cvt;
    cvt.h2 = __float22bfloat162_rn(make_float2(a, b));   // v_cvt_pk_bf16_f32
    return cvt.u;
}

__device__ __forceinline__ void gl_lds16(const ushort_t* g, ushort_t* l) {
    __builtin_amdgcn_global_load_lds(
        (const __attribute__((address_space(1))) unsigned int*)g,
        (__attribute__((address_space(3))) unsigned int*)l, 16, 0, 0);
}

// K=16 bf16 MFMA: A/B = 4 bf16 (2 VGPRs). S^T C-frag == PV A-frag for this shape.
__device__ __forceinline__ f32x4 mfma16(uint2_t a, uint2_t b, f32x4 c) {
    union { uint2_t u; bf16x4_t s; } ua, ub;
    ua.u = a; ub.u = b;
    return __builtin_amdgcn_mfma_f32_16x16x16bf16_1k(ua.s, ub.s, c, 0, 0, 0);
}

// ---------------------------------------------------------------------------
// Merged conversion kernel (one launch instead of two):
//  blocks [0, 4096):    x (fp32 [8192][1024]) -> xb (bf16, same layout)
//  blocks [4096, 5632): w (fp32 [1024][3072]) -> wt (bf16 [3072][1024]) transp
// ---------------------------------------------------------------------------
__global__ __launch_bounds__(256) void cvt_xw(
    const float* __restrict__ x, ushort_t* __restrict__ xb,
    const float* __restrict__ w, ushort_t* __restrict__ wt)
{
    __shared__ ushort_t Ts[64][40];           // [n][k] (w path only)
    const int bid = blockIdx.x;
    const int tid = threadIdx.x;
    if (bid < 4096) {
        const size_t i = ((size_t)bid * 256 + tid) * 8;
        const float4 a = *(const float4*)(x + i);
        const float4 b = *(const float4*)(x + i + 4);
        uint4_t o;
        o[0] = pk2bf(a.x, a.y); o[1] = pk2bf(a.z, a.w);
        o[2] = pk2bf(b.x, b.y); o[3] = pk2bf(b.z, b.w);
        *(uint4_t*)(xb + i) = o;
    } else {
        const int wb = bid - 4096;
        const int k0 = (wb & 31) * 32, n0 = (wb >> 5) * 64;
        const int kr = tid >> 3, nc = (tid & 7) * 8;
        const float* g = w + (size_t)(k0 + kr) * 3072 + n0 + nc;
        const float4 a = *(const float4*)g;
        const float4 b = *(const float4*)(g + 4);
        const float vals[8] = {a.x, a.y, a.z, a.w, b.x, b.y, b.z, b.w};
#pragma unroll
        for (int j = 0; j < 8; ++j) Ts[nc + j][kr] = f2bf(vals[j]);
        __syncthreads();
        const int nr = tid >> 2, kc = (tid & 3) * 8;
        const short8 v = *(const short8*)&Ts[nr][kc];
        *(short8*)(wt + (size_t)(n0 + nr) * 1024 + k0 + kc) = v;
    }
}

// ---------------------------------------------------------------------------
// qkv = xb @ wt^T + b.  BM=128, BN=256, BK=32, 512 threads / 8 waves (2Mx4N).
// Same T3+T4 pipeline as round 3 (3 LDS buffers, prefetch distance 2, raw
// s_barrier + counted vmcnt, never 0 in main loop), but the wider tile cuts
// barrier intervals from 64 to 48 (768 blocks at 2/CU = 1.5 generations x 32
// steps) and raises residency to 16 waves/CU (LDS 72 KB -> 2 blocks/CU).
// Per-wave work per step unchanged: 16 MFMA, 8 ds_read_b128, 3 gl_lds16
// (A:1 + B:2) -> vmcnt(3) keeps one future tile in flight.
// LDS slot (R,c16B) holds data (R, c ^ ((R>>1)&3)): staging fetches the
// permuted chunk (same 64B line per 4-lane quad -> coalescing intact), the
// fragment ds_read_b128 at chunk quad^((qr>>1)&3) is bank-conflict-free.
// Epilogue: +bias; K,Q -> [bh][t][d]; V -> [bh][d][t].
// ---------------------------------------------------------------------------
__global__ __launch_bounds__(512) void qkv_gemm(
    const ushort_t* __restrict__ xb, const ushort_t* __restrict__ wt,
    const float* __restrict__ bq,
    ushort_t* __restrict__ kws, ushort_t* __restrict__ qws,
    ushort_t* __restrict__ vws)
{
    __shared__ ushort_t As[3][128 * 32];      // [buf][row][k] 24 KB
    __shared__ ushort_t Bs[3][256 * 32];      // [buf][row][k] 48 KB

    const int tid  = threadIdx.x;
    const int m0   = blockIdx.x * 128;
    const int n0   = blockIdx.y * 256;
    const int wv   = tid >> 6;                // 0..7
    const int lane = tid & 63;
    const int qr   = lane & 15;
    const int quad = lane >> 4;
    const int wm   = (wv >> 2) * 64;          // 0 or 64   (2 M-waves)
    const int wn   = (wv & 3) * 64;           // 0..192    (4 N-waves)

    // staging: A rows wv*16 + lr (1 load); B rows wv*32 + lr (+16) (2 loads)
    const int lr   = lane >> 2;               // 0..15
    const int csw  = (lane & 3) ^ ((lr >> 1) & 3);
    const ushort_t* gA = xb + (size_t)(m0 + wv*16 + lr) * 1024 + csw*8;
    const ushort_t* gB = wt + (size_t)(n0 + wv*32 + lr) * 1024 + csw*8;
    const int sdstA = wv * 512;               // ushort offset in an A buffer
    const int sdstB = wv * 1024;              // ushort offset in a B buffer

    const int swq = quad ^ ((qr >> 1) & 3);   // swizzled fragment chunk

    f32x4 acc[4][4];
#pragma unroll
    for (int i = 0; i < 4; ++i)
#pragma unroll
        for (int j = 0; j < 4; ++j) acc[i][j] = (f32x4){0.f, 0.f, 0.f, 0.f};

    // prologue: stage tiles 0 and 1 into bufs 0 and 1 (6 loads in flight)
    gl_lds16(gA,                 (ushort_t*)As + sdstA);
    gl_lds16(gB,                 (ushort_t*)Bs + sdstB);
    gl_lds16(gB + 16*1024,       (ushort_t*)Bs + sdstB + 512);
    gl_lds16(gA + 32,            (ushort_t*)As + 4096 + sdstA);
    gl_lds16(gB + 32,            (ushort_t*)Bs + 8192 + sdstB);
    gl_lds16(gB + 32 + 16*1024,  (ushort_t*)Bs + 8192 + sdstB + 512);

    int bufc = 0;                             // kt % 3
    for (int kt = 0; kt < 32; ++kt) {
        // tile kt's 3 own loads must be complete; tile kt+1's 3 stay in
        // flight across the barrier (T4). Last tile: full drain.
        if (kt < 31) asm volatile("s_waitcnt vmcnt(3)" ::: "memory");
        else         asm volatile("s_waitcnt vmcnt(0)" ::: "memory");
        __builtin_amdgcn_s_barrier();         // buf[kt%3] ready for everyone
        __builtin_amdgcn_sched_barrier(0);

        const ushort_t* cA = (const ushort_t*)As + bufc * 4096;
        const ushort_t* cB = (const ushort_t*)Bs + bufc * 8192;
        short8 af[4], bfr[4];
#pragma unroll
        for (int i = 0; i < 4; ++i)
            af[i] = *(const short8*)&cA[(wm + i*16 + qr) * 32 + swq * 8];
#pragma unroll
        for (int j = 0; j < 4; ++j)
            bfr[j] = *(const short8*)&cB[(wn + j*16 + qr) * 32 + swq * 8];

        if (kt < 30) {                        // stage tile kt+2
            int b2 = bufc + 2;
            if (b2 >= 3) b2 -= 3;
            const int k2 = (kt + 2) * 32;
            gl_lds16(gA + k2,            (ushort_t*)As + b2*4096 + sdstA);
            gl_lds16(gB + k2,            (ushort_t*)Bs + b2*8192 + sdstB);
            gl_lds16(gB + k2 + 16*1024,  (ushort_t*)Bs + b2*8192 + sdstB + 512);
        }

#pragma unroll
        for (int i = 0; i < 4; ++i)
#pragma unroll
            for (int j = 0; j < 4; ++j)
                acc[i][j] = __builtin_amdgcn_mfma_f32_16x16x32_bf16(
                    af[i], bfr[j], acc[i][j], 0, 0, 0);

        // all my ds_reads of buf[kt%3] serviced before next barrier releases
        // writers into it (WAR). Near-free: MFMAs already consumed them.
        asm volatile("s_waitcnt lgkmcnt(0)" ::: "memory");
        bufc = (bufc == 2) ? 0 : bufc + 1;
    }

    const int nbase = n0 + wn;                // 64-col section, wave-uniform
    const int sec   = nbase >> 10;            // 0=K, 1=Q, 2=V
    const int h     = (nbase & 1023) >> 6;

    if (sec == 2) {
#pragma unroll
        for (int j = 0; j < 4; ++j) {
            const float bias = bq[nbase + j*16 + qr];
            const int d = j*16 + qr;
#pragma unroll
            for (int i = 0; i < 4; ++i) {
                const int m  = m0 + wm + i*16 + quad*4;
                const int bb = m >> 11;
                const int tt = m & 2047;
                ushort4_t pk;
#pragma unroll
                for (int r = 0; r < 4; ++r) pk[r] = f2bf(acc[i][j][r] + bias);
                *(ushort4_t*)&vws[((size_t)(bb*16 + h)*64 + d)*2048 + tt] = pk;
            }
        }
    } else {
        ushort_t* __restrict__ dst = (sec == 0) ? kws : qws;
#pragma unroll
        for (int j = 0; j < 4; ++j) {
            const float bias = bq[nbase + j*16 + qr];
            const int d = j*16 + qr;
#pragma unroll
            for (int i = 0; i < 4; ++i) {
#pragma unroll
                for (int r = 0; r < 4; ++r) {
                    const int m  = m0 + wm + i*16 + quad*4 + r;
                    const int bb = m >> 11;
                    const int tt = m & 2047;
                    dst[(((size_t)(bb*16 + h)) * 2048 + tt) * 64 + d] =
                        f2bf(acc[i][j][r] + bias);
                }
            }
        }
    }
}

// ---------------------------------------------------------------------------
// Causal flash attention — exact round-4 configuration (best measured:
// 82.1 us, 40 VGPR). 512 threads / 8 waves; wave owns 16 q-rows; ONE q-tile
// per block; grid 1024 = 16 qt x 64 bh; LPT order (qt=15 first); bh = bid&63
// keeps a head's blocks on one XCD (FETCH -5x). 36 KB LDS -> 4 blocks/CU.
// Double-buffered K/V staged through registers, constant-max softmax fused
// per 16-key chunk, PV from registers via 16x16x16 MFMA.
// ---------------------------------------------------------------------------
__global__ __launch_bounds__(512) void attn_fwd(
    const ushort_t* __restrict__ kws, const ushort_t* __restrict__ qws,
    const ushort_t* __restrict__ vws, float* __restrict__ out)
{
    constexpr int LDK = 72;                   // 64 + 8 pad (rows 16B-aligned)
    __shared__ ushort_t Ks[2][64 * LDK];      // [buf][key][d]
    __shared__ ushort_t Vs[2][64 * LDK];      // [buf][d][t]

    const int tid  = threadIdx.x;
    const int wv   = tid >> 6;                // 0..7
    const int lane = tid & 63;
    const int qr   = lane & 15;
    const int quad = lane >> 4;
    const int srow = tid >> 3;                // 0..63
    const int scol = (tid & 7) * 8;           // 0..56
    constexpr float SCL = 0.125f * LOG2E;     // 1/sqrt(64), log2 domain
    constexpr float CB  = 8.0f;               // fixed max bound (log2 units)

    const int bid = (int)blockIdx.x;
    const int qt  = 15 - (bid >> 6);          // LPT: longest blocks first
    const int bh  = bid & 63;
    const size_t bhT = (size_t)bh * 2048;
    const ushort_t* kbase = kws + bhT * 64;
    const ushort_t* vbase = vws + (size_t)bh * 64 * 2048;
    const int b = bh >> 4, h = bh & 15;

    const int q0   = qt * 128;
    const int base = q0 + wv*16;              // this wave's 16 q-rows
    const int qv0  = base + qr;               // softmax-domain q (q = lane&15)

    const ushort_t* qg0 = qws + (bhT + qv0) * 64;
    const short8 Qb00 = *(const short8*)(qg0 + quad*8);
    const short8 Qb01 = *(const short8*)(qg0 + 32 + quad*8);

    float l_s = 0.f;
    f32x4 Oacc[4];
#pragma unroll
    for (int dt = 0; dt < 4; ++dt) Oacc[dt] = (f32x4){0.f,0.f,0.f,0.f};

    const int nkt = 2*qt + 2;
    const int row_max = base + 15;

    // prologue: tile 0 -> regs -> buf0
    short8 kv0, vv0;
    {
        const ushort_t* kg = kbase + (size_t)srow * 64 + scol;
        const ushort_t* vg = vbase + (size_t)srow * 2048 + scol;
        kv0 = *(const short8*)(kg);
        vv0 = *(const short8*)(vg);
    }
    *(short8*)&Ks[0][srow * LDK + scol] = kv0;
    *(short8*)&Vs[0][srow * LDK + scol] = vv0;
    __syncthreads();

    for (int kt = 0; kt < nkt; ++kt) {
        const int k0 = kt * 64;
        const int cur = kt & 1;
        const bool more = (kt + 1 < nkt);
        if (more) {                           // issue next-tile loads (in flight)
            const ushort_t* kg = kbase + (size_t)(k0 + 64 + srow) * 64 + scol;
            const ushort_t* vg = vbase + (size_t)srow * 2048 + k0 + 64 + scol;
            kv0 = *(const short8*)(kg);
            vv0 = *(const short8*)(vg);
        }

        if (k0 <= row_max) {
            const ushort_t* Kc = Ks[cur];
            const ushort_t* Vc = Vs[cur];
            const bool diag = (k0 + 63 > base);   // wave-uniform

            // Per 16-key chunk: S^T = K Q^T, mask, exp2, pack -> pks.
            uint2_t pks[4];
            float ps0 = 0.f;
#pragma unroll
            for (int t4 = 0; t4 < 4; ++t4) {
                const short8 kf0 = *(const short8*)&Kc[(t4*16 + qr)*LDK + quad*8];
                const short8 kf1 = *(const short8*)&Kc[(t4*16 + qr)*LDK + 32 + quad*8];
                f32x4 a = (f32x4){0.f,0.f,0.f,0.f};
                a = __builtin_amdgcn_mfma_f32_16x16x32_bf16(kf0, Qb00, a, 0,0,0);
                a = __builtin_amdgcn_mfma_f32_16x16x32_bf16(kf1, Qb01, a, 0,0,0);
                if (diag) {
#pragma unroll
                    for (int r = 0; r < 4; ++r) {
                        const int key = k0 + t4*16 + quad*4 + r;
                        if (key > qv0) a[r] = -INFINITY;
                    }
                }
                float p0[4];
#pragma unroll
                for (int r = 0; r < 4; ++r) {
                    p0[r] = exp2f(__builtin_fmaf(a[r], SCL, -CB));
                    ps0 += p0[r];
                }
                pks[t4][0] = pk2bf(p0[0], p0[1]);
                pks[t4][1] = pk2bf(p0[2], p0[3]);
            }
            l_s += ps0;

            // O += P V : B-frag = V[key][d] from Vs[d][t], k=quad*4..+3
            __builtin_amdgcn_s_setprio(1);
#pragma unroll
            for (int dt = 0; dt < 4; ++dt) {
#pragma unroll
                for (int t4 = 0; t4 < 4; ++t4) {
                    const uint2_t vf = *(const uint2_t*)
                        &Vc[(dt*16 + qr)*LDK + t4*16 + quad*4];
                    Oacc[dt] = mfma16(pks[t4], vf, Oacc[dt]);
                }
            }
            __builtin_amdgcn_s_setprio(0);
        }

        if (more) {                           // stage tile kt+1 into other buf
            *(short8*)&Ks[cur ^ 1][srow * LDK + scol] = kv0;
            *(short8*)&Vs[cur ^ 1][srow * LDK + scol] = vv0;
        }
        __syncthreads();                      // buf ready / reads of cur done
    }

    // epilogue: reduce l across quads, store
    float lf = l_s;
    lf += __shfl_xor(lf, 16);
    lf += __shfl_xor(lf, 32);
#pragma unroll
    for (int r = 0; r < 4; ++r) {
        const float lr  = __shfl(lf, quad*4 + r);
        const float inv = 1.f / lr;
        const int q = q0 + wv*16 + quad*4 + r;
        float* o = out + ((size_t)(b*2048 + q)) * 1024 + h*64;
#pragma unroll
        for (int dt = 0; dt < 4; ++dt) o[dt*16 + qr] = Oacc[dt][r] * inv;
    }
}

extern "C" void kernel_launch(void* const* d_in, const int* in_sizes, int n_in,
                              void* d_out, int out_size, void* d_ws, size_t ws_size,
                              hipStream_t stream) {
    (void)in_sizes; (void)n_in; (void)out_size; (void)ws_size;
    const float* x  = (const float*)d_in[0];
    const float* w  = (const float*)d_in[1];
    const float* bq = (const float*)d_in[2];
    float* out = (float*)d_out;

    ushort_t* kws = (ushort_t*)d_ws;
    ushort_t* qws = kws + (size_t)8388608;
    ushort_t* vws = qws + (size_t)8388608;
    ushort_t* xb  = vws + (size_t)8388608;
    ushort_t* wt  = xb  + (size_t)8388608;

    cvt_xw<<<5632, 256, 0, stream>>>(x, xb, w, wt);
    qkv_gemm<<<dim3(64, 12), 512, 0, stream>>>(xb, wt, bq, kws, qws, vws);
    attn_fwd<<<1024, 512, 0, stream>>>(kws, qws, vws, out);
}